// Round 1
// baseline (1000.823 us; speedup 1.0000x reference)
//
#include <hip/hip_runtime.h>
#include <stdint.h>

#define NNODES 50000
#define NREL 4
#define NEDGES 250000
#define INF 512
#define HIDF 512
#define OUTF 256
#define KCAT 2560   // 5 * 512

typedef unsigned short u16;
typedef u16 u16x8 __attribute__((ext_vector_type(8)));
typedef __bf16 bf16x8 __attribute__((ext_vector_type(8)));
typedef float f32x4 __attribute__((ext_vector_type(4)));

__device__ __forceinline__ float bf2f(u16 b) {
    unsigned u = ((unsigned)b) << 16;
    return __builtin_bit_cast(float, u);
}
__device__ __forceinline__ u16 f2bf(float f) {
    unsigned u = __builtin_bit_cast(unsigned, f);
    u = (u + 0x7fffu + ((u >> 16) & 1u)) >> 16;
    return (u16)u;
}

#define GLOAD_LDS16(gsrc, ldst)                                                  \
    __builtin_amdgcn_global_load_lds(                                            \
        (__attribute__((address_space(1))) void*)(gsrc),                         \
        (__attribute__((address_space(3))) void*)(ldst), 16, 0, 0)

// ---------------- setup kernels ----------------

__global__ void cast_bf16_kernel(const float* __restrict__ in, u16* __restrict__ out, long total) {
    long i = ((long)blockIdx.x * blockDim.x + threadIdx.x) * 8;
    long stride = (long)gridDim.x * blockDim.x * 8;
    for (; i + 7 < total; i += stride) {
        float4 v0 = *(const float4*)(in + i);
        float4 v1 = *(const float4*)(in + i + 4);
        u16x8 o;
        o[0] = f2bf(v0.x); o[1] = f2bf(v0.y); o[2] = f2bf(v0.z); o[3] = f2bf(v0.w);
        o[4] = f2bf(v1.x); o[5] = f2bf(v1.y); o[6] = f2bf(v1.z); o[7] = f2bf(v1.w);
        *(u16x8*)(out + i) = o;
    }
}

// WT[n][s*512 + k]; s=0 -> sum_r Wself[r][k][n]; s=1..4 -> Wneigh[s-1][k][n]
__global__ void prep_w_kernel(const float* __restrict__ Wself, const float* __restrict__ Wneigh,
                              u16* __restrict__ WT, int N) {
    int total = N * KCAT;
    for (int idx = blockIdx.x * blockDim.x + threadIdx.x; idx < total;
         idx += gridDim.x * blockDim.x) {
        int n = idx / KCAT;
        int kg = idx - n * KCAT;
        int s = kg >> 9;
        int k = kg & 511;
        float v;
        if (s == 0) {
            v = Wself[(size_t)k * N + n] + Wself[(size_t)(512 + k) * N + n] +
                Wself[(size_t)(1024 + k) * N + n] + Wself[(size_t)(1536 + k) * N + n];
        } else {
            v = Wneigh[((size_t)(s - 1) * 512 + k) * N + n];
        }
        WT[idx] = f2bf(v);
    }
}

__global__ void prep_bias_kernel(const float* __restrict__ b1, const float* __restrict__ b2,
                                 float* __restrict__ b1s, float* __restrict__ b2s) {
    int t = threadIdx.x;
    if (t < HIDF) b1s[t] = b1[t] + b1[HIDF + t] + b1[2 * HIDF + t] + b1[3 * HIDF + t];
    if (t < OUTF) b2s[t] = b2[t] + b2[OUTF + t] + b2[2 * OUTF + t] + b2[3 * OUTF + t];
}

// ---------------- CSR build ----------------

__global__ void hist_kernel(const int* __restrict__ dst, int* __restrict__ deg) {
    int tot = NREL * NEDGES;
    for (int i = blockIdx.x * blockDim.x + threadIdx.x; i < tot; i += gridDim.x * blockDim.x) {
        int r = i / NEDGES;
        atomicAdd(&deg[r * NNODES + dst[i]], 1);
    }
}

__global__ __launch_bounds__(1024) void scan_kernel(const int* __restrict__ deg,
                                                    int* __restrict__ rp, int* __restrict__ cur) {
    int r = blockIdx.x;
    const int* d = deg + r * NNODES;
    int* out = rp + r * (NNODES + 1);
    int* cu = cur + r * NNODES;
    __shared__ int wsum[16];
    __shared__ int carryS;
    int lane = threadIdx.x & 63, wid = threadIdx.x >> 6;
    if (threadIdx.x == 0) carryS = 0;
    __syncthreads();
    for (int base = 0; base < NNODES; base += 1024) {
        int i = base + threadIdx.x;
        int v = (i < NNODES) ? d[i] : 0;
        int x = v;
#pragma unroll
        for (int off = 1; off < 64; off <<= 1) {
            int o = __shfl_up(x, off);
            if (lane >= off) x += o;
        }
        if (lane == 63) wsum[wid] = x;
        __syncthreads();
        if (wid == 0) {
            int s = (lane < 16) ? wsum[lane] : 0;
#pragma unroll
            for (int off = 1; off < 16; off <<= 1) {
                int o = __shfl_up(s, off);
                if (lane >= off) s += o;
            }
            if (lane < 16) wsum[lane] = s;
        }
        __syncthreads();
        int wpre = (wid > 0) ? wsum[wid - 1] : 0;
        int incl = carryS + wpre + x;
        int excl = incl - v;
        if (i < NNODES) { out[i] = excl; cu[i] = excl; }
        __syncthreads();
        if (threadIdx.x == 1023) carryS = incl;
        __syncthreads();
    }
    if (threadIdx.x == 0) out[NNODES] = carryS;
}

__global__ void fill_kernel(const int* __restrict__ esrc, const int* __restrict__ edst,
                            int* __restrict__ cur, int* __restrict__ col) {
    int tot = NREL * NEDGES;
    for (int i = blockIdx.x * blockDim.x + threadIdx.x; i < tot; i += gridDim.x * blockDim.x) {
        int r = i / NEDGES;
        int d = edst[i];
        int pos = atomicAdd(&cur[r * NNODES + d], 1);
        col[r * NEDGES + pos] = esrc[i];
    }
}

// ---------------- aggregation: one wave per (node, rel) ----------------
// out[rel][node][f] = (sum_{e in CSR_rel[node]} src[col[e]][f]) / max(deg,1), bf16

__global__ void aggregate_kernel(const u16* __restrict__ src, const int* __restrict__ rp,
                                 const int* __restrict__ col, u16* __restrict__ out) {
    int node = blockIdx.x * 4 + (threadIdx.x >> 6);
    int rel = blockIdx.y;
    if (node >= NNODES) return;
    const int* r = rp + rel * (NNODES + 1);
    const int* cl = col + rel * NEDGES;
    int l = threadIdx.x & 63;
    int p0 = r[node], p1 = r[node + 1];
    float scale = (p1 > p0) ? 1.0f / (float)(p1 - p0) : 1.0f;
    float acc[8] = {0.f, 0.f, 0.f, 0.f, 0.f, 0.f, 0.f, 0.f};
    for (int e = p0; e < p1; ++e) {
        int s = cl[e];
        u16x8 v = *(const u16x8*)(src + (size_t)s * 512 + l * 8);
#pragma unroll
        for (int j = 0; j < 8; ++j) acc[j] += bf2f(v[j]);
    }
    u16x8 o;
#pragma unroll
    for (int j = 0; j < 8; ++j) o[j] = f2bf(acc[j] * scale);
    *(u16x8*)(out + ((size_t)rel * NNODES + node) * 512 + l * 8) = o;
}

// ---------------- GEMM: C[M][N] = concat_K(A0..A4) @ WT^T + bias ----------------
// A_s: [M][512] bf16 row-major.  WT: [N][2560] bf16 row-major (pre-transposed weights).
// OUTMODE 0: out = bf16(relu(acc+bias));  OUTMODE 1: out = f32(acc+bias)

template <int N, int OUTMODE>
__global__ __launch_bounds__(256, 2) void gemm_kernel(
    const u16* __restrict__ A0, const u16* __restrict__ A1, const u16* __restrict__ A2,
    const u16* __restrict__ A3, const u16* __restrict__ A4, const u16* __restrict__ WT,
    const float* __restrict__ bias, void* __restrict__ outp, int M) {
    __shared__ u16 ldsA[128 * 64];
    __shared__ u16 ldsB[128 * 64];
    const int t = threadIdx.x;
    const int w = t >> 6, l = t & 63;
    const int wr = w >> 1, wc = w & 1;
    const int rowBase = blockIdx.x * 128;
    const int colBase = blockIdx.y * 128;

    f32x4 acc[4][4] = {};

    const u16* const As[5] = {A0, A1, A2, A3, A4};
    const int sr = t >> 3;       // 0..31 staging row within a call
    const int gp = t & 7;        // physical granule (16B)
    const int lr = l & 15, lg = l >> 4;

#pragma unroll
    for (int s = 0; s < 5; ++s) {
        const u16* __restrict__ Asrc = As[s];
        for (int ts = 0; ts < 8; ++ts) {
            const int klocal = ts * 64;
            const int kglob = s * 512 + klocal;
            // stage A tile (128 x 64 bf16), pre-swizzled source, linear LDS dest
#pragma unroll
            for (int c = 0; c < 4; ++c) {
                int r = c * 32 + sr;
                int gl = gp ^ (r & 7);
                int grow = rowBase + r;
                if (grow > M - 1) grow = M - 1;
                const u16* gsrc = Asrc + (size_t)grow * 512 + klocal + gl * 8;
                GLOAD_LDS16(gsrc, ldsA + (c * 2048 + w * 512));
            }
            // stage B tile (128 output-cols x 64 k)
#pragma unroll
            for (int c = 0; c < 4; ++c) {
                int r = c * 32 + sr;
                int gl = gp ^ (r & 7);
                const u16* gsrc = WT + (size_t)(colBase + r) * KCAT + kglob + gl * 8;
                GLOAD_LDS16(gsrc, ldsB + (c * 2048 + w * 512));
            }
            __syncthreads();   // drains vmcnt before any wave reads LDS
#pragma unroll
            for (int kh = 0; kh < 2; ++kh) {
                bf16x8 av[4], bv[4];
#pragma unroll
                for (int m = 0; m < 4; ++m) {
                    int r = wr * 64 + m * 16 + lr;
                    int g = (kh * 4 + lg) ^ (r & 7);
                    av[m] = *(const bf16x8*)((const char*)ldsA + r * 128 + g * 16);
                }
#pragma unroll
                for (int n = 0; n < 4; ++n) {
                    int r = wc * 64 + n * 16 + lr;
                    int g = (kh * 4 + lg) ^ (r & 7);
                    bv[n] = *(const bf16x8*)((const char*)ldsB + r * 128 + g * 16);
                }
#pragma unroll
                for (int m = 0; m < 4; ++m)
#pragma unroll
                    for (int n = 0; n < 4; ++n)
                        acc[m][n] =
                            __builtin_amdgcn_mfma_f32_16x16x32_bf16(av[m], bv[n], acc[m][n], 0, 0, 0);
            }
            __syncthreads();   // compute done before next stage overwrites
        }
    }

    const int lq = l >> 4;
#pragma unroll
    for (int m = 0; m < 4; ++m) {
#pragma unroll
        for (int n = 0; n < 4; ++n) {
#pragma unroll
            for (int j = 0; j < 4; ++j) {
                int row = rowBase + wr * 64 + m * 16 + lq * 4 + j;
                int colc = colBase + wc * 64 + n * 16 + lr;
                if (row < M) {
                    float v = acc[m][n][j] + bias[colc];
                    if (OUTMODE == 0) {
                        v = v > 0.f ? v : 0.f;
                        ((u16*)outp)[(size_t)row * N + colc] = f2bf(v);
                    } else {
                        ((float*)outp)[(size_t)row * N + colc] = v;
                    }
                }
            }
        }
    }
}

// ---------------- host ----------------

extern "C" void kernel_launch(void* const* d_in, const int* in_sizes, int n_in,
                              void* d_out, int out_size, void* d_ws, size_t ws_size,
                              hipStream_t stream) {
    const float* x = (const float*)d_in[0];
    const float* Wself1 = (const float*)d_in[1];
    const float* Wneigh1 = (const float*)d_in[2];
    const float* b1 = (const float*)d_in[3];
    const float* Wself2 = (const float*)d_in[4];
    const float* Wneigh2 = (const float*)d_in[5];
    const float* b2 = (const float*)d_in[6];
    const int* esrc = (const int*)d_in[7];
    const int* edst = (const int*)d_in[8];

    char* ws = (char*)d_ws;
    size_t off = 0;
    auto alloc = [&](size_t bytes) {
        char* p = ws + off;
        off += (bytes + 255) & ~(size_t)255;
        return p;
    };
    const size_t plane = (size_t)NNODES * 512;
    u16* xB = (u16*)alloc(plane * 2);             // x in bf16
    u16* mB = (u16*)alloc(NREL * plane * 2);      // 4 aggregate buffers
    u16* h1B = (u16*)alloc(plane * 2);            // relu(h1) in bf16
    u16* WT1 = (u16*)alloc((size_t)HIDF * KCAT * 2);
    u16* WT2 = (u16*)alloc((size_t)OUTF * KCAT * 2);
    float* b1s = (float*)alloc(HIDF * 4);
    float* b2s = (float*)alloc(OUTF * 4);
    int* deg = (int*)alloc((size_t)NREL * NNODES * 4);
    int* rp = (int*)alloc((size_t)NREL * (NNODES + 1) * 4);
    int* cur = (int*)alloc((size_t)NREL * NNODES * 4);
    int* col = (int*)alloc((size_t)NREL * NEDGES * 4);

    hipMemsetAsync(deg, 0, (size_t)NREL * NNODES * 4, stream);
    cast_bf16_kernel<<<12500, 256, 0, stream>>>(x, xB, (long)NNODES * INF);
    prep_w_kernel<<<1280, 256, 0, stream>>>(Wself1, Wneigh1, WT1, HIDF);
    prep_w_kernel<<<640, 256, 0, stream>>>(Wself2, Wneigh2, WT2, OUTF);
    prep_bias_kernel<<<1, 512, 0, stream>>>(b1, b2, b1s, b2s);
    hist_kernel<<<1024, 256, 0, stream>>>(edst, deg);
    scan_kernel<<<4, 1024, 0, stream>>>(deg, rp, cur);
    fill_kernel<<<1024, 256, 0, stream>>>(esrc, edst, cur, col);

    // layer 1
    aggregate_kernel<<<dim3(12500, 4), 256, 0, stream>>>(xB, rp, col, mB);
    gemm_kernel<HIDF, 0><<<dim3(391, 4), 256, 0, stream>>>(
        xB, mB, mB + plane, mB + 2 * plane, mB + 3 * plane, WT1, b1s, h1B, NNODES);

    // layer 2
    aggregate_kernel<<<dim3(12500, 4), 256, 0, stream>>>(h1B, rp, col, mB);
    gemm_kernel<OUTF, 1><<<dim3(391, 2), 256, 0, stream>>>(
        h1B, mB, mB + plane, mB + 2 * plane, mB + 3 * plane, WT2, b2s, d_out, NNODES);
}

// Round 2
// 855.557 us; speedup vs baseline: 1.1698x; 1.1698x over previous
//
#include <hip/hip_runtime.h>
#include <stdint.h>

#define NNODES 50000
#define NREL 4
#define NEDGES 250000
#define INF 512
#define HIDF 512
#define OUTF 256
#define KCAT 2560   // 5 * 512
#define SCANB 49    // ceil(50000/1024)

typedef unsigned short u16;
typedef u16 u16x8 __attribute__((ext_vector_type(8)));
typedef __bf16 bf16x8 __attribute__((ext_vector_type(8)));
typedef float f32x4 __attribute__((ext_vector_type(4)));

__device__ __forceinline__ float bf2f(u16 b) {
    unsigned u = ((unsigned)b) << 16;
    return __builtin_bit_cast(float, u);
}
__device__ __forceinline__ u16 f2bf(float f) {
    unsigned u = __builtin_bit_cast(unsigned, f);
    u = (u + 0x7fffu + ((u >> 16) & 1u)) >> 16;
    return (u16)u;
}

#define GLOAD_LDS16(gsrc, ldst)                                                  \
    __builtin_amdgcn_global_load_lds(                                            \
        (__attribute__((address_space(1))) void*)(gsrc),                         \
        (__attribute__((address_space(3))) void*)(ldst), 16, 0, 0)

// ---------------- setup kernels ----------------

__global__ void cast_bf16_kernel(const float* __restrict__ in, u16* __restrict__ out, long total) {
    long i = ((long)blockIdx.x * blockDim.x + threadIdx.x) * 8;
    long stride = (long)gridDim.x * blockDim.x * 8;
    for (; i + 7 < total; i += stride) {
        float4 v0 = *(const float4*)(in + i);
        float4 v1 = *(const float4*)(in + i + 4);
        u16x8 o;
        o[0] = f2bf(v0.x); o[1] = f2bf(v0.y); o[2] = f2bf(v0.z); o[3] = f2bf(v0.w);
        o[4] = f2bf(v1.x); o[5] = f2bf(v1.y); o[6] = f2bf(v1.z); o[7] = f2bf(v1.w);
        *(u16x8*)(out + i) = o;
    }
}

// WT[n][s*512 + k]; s=0 -> sum_r Wself[r][k][n]; s=1..4 -> Wneigh[s-1][k][n]
__global__ void prep_w_kernel(const float* __restrict__ Wself, const float* __restrict__ Wneigh,
                              u16* __restrict__ WT, int N) {
    int total = N * KCAT;
    for (int idx = blockIdx.x * blockDim.x + threadIdx.x; idx < total;
         idx += gridDim.x * blockDim.x) {
        int n = idx / KCAT;
        int kg = idx - n * KCAT;
        int s = kg >> 9;
        int k = kg & 511;
        float v;
        if (s == 0) {
            v = Wself[(size_t)k * N + n] + Wself[(size_t)(512 + k) * N + n] +
                Wself[(size_t)(1024 + k) * N + n] + Wself[(size_t)(1536 + k) * N + n];
        } else {
            v = Wneigh[((size_t)(s - 1) * 512 + k) * N + n];
        }
        WT[idx] = f2bf(v);
    }
}

__global__ void prep_bias_kernel(const float* __restrict__ b1, const float* __restrict__ b2,
                                 float* __restrict__ b1s, float* __restrict__ b2s) {
    int t = threadIdx.x;
    if (t < HIDF) b1s[t] = b1[t] + b1[HIDF + t] + b1[2 * HIDF + t] + b1[3 * HIDF + t];
    if (t < OUTF) b2s[t] = b2[t] + b2[OUTF + t] + b2[2 * OUTF + t] + b2[3 * OUTF + t];
}

// ---------------- CSR build ----------------

__global__ void hist_kernel(const int* __restrict__ dst, int* __restrict__ deg) {
    int tot = NREL * NEDGES;
    for (int i = blockIdx.x * blockDim.x + threadIdx.x; i < tot; i += gridDim.x * blockDim.x) {
        int r = i / NEDGES;
        atomicAdd(&deg[r * NNODES + dst[i]], 1);
    }
}

// 3-kernel scan: per-block exclusive scan + block sums -> scan block sums -> add offsets
__global__ __launch_bounds__(1024) void scan1_kernel(const int* __restrict__ deg,
                                                     int* __restrict__ rp, int* __restrict__ bsum) {
    int rel = blockIdx.x / SCANB, blk = blockIdx.x % SCANB;
    int i = blk * 1024 + threadIdx.x;
    int v = (i < NNODES) ? deg[rel * NNODES + i] : 0;
    __shared__ int wsum[16];
    int lane = threadIdx.x & 63, wid = threadIdx.x >> 6;
    int x = v;
#pragma unroll
    for (int off = 1; off < 64; off <<= 1) {
        int o = __shfl_up(x, off);
        if (lane >= off) x += o;
    }
    if (lane == 63) wsum[wid] = x;
    __syncthreads();
    if (wid == 0) {
        int s = (lane < 16) ? wsum[lane] : 0;
#pragma unroll
        for (int off = 1; off < 16; off <<= 1) {
            int o = __shfl_up(s, off);
            if (lane >= off) s += o;
        }
        if (lane < 16) wsum[lane] = s;
    }
    __syncthreads();
    int excl = (wid > 0 ? wsum[wid - 1] : 0) + x - v;
    if (i < NNODES) rp[rel * (NNODES + 1) + i] = excl;
    if (threadIdx.x == 1023) bsum[blockIdx.x] = excl + v;
}

__global__ void scan2_kernel(const int* __restrict__ bsum, int* __restrict__ bofs) {
    int r = threadIdx.x >> 6, lane = threadIdx.x & 63;  // 4 waves, one per rel
    int v = (lane < SCANB) ? bsum[r * SCANB + lane] : 0;
    int x = v;
#pragma unroll
    for (int off = 1; off < 64; off <<= 1) {
        int o = __shfl_up(x, off);
        if (lane >= off) x += o;
    }
    if (lane < SCANB) bofs[r * SCANB + lane] = x - v;
}

__global__ __launch_bounds__(1024) void scan3_kernel(int* __restrict__ rp, int* __restrict__ cur,
                                                     const int* __restrict__ bofs) {
    int rel = blockIdx.x / SCANB, blk = blockIdx.x % SCANB;
    int i = blk * 1024 + threadIdx.x;
    if (i < NNODES) {
        int v = rp[rel * (NNODES + 1) + i] + bofs[rel * SCANB + blk];
        rp[rel * (NNODES + 1) + i] = v;
        cur[rel * NNODES + i] = v;
        if (i == 0) rp[rel * (NNODES + 1) + NNODES] = NEDGES;
    }
}

__global__ void fill_kernel(const int* __restrict__ esrc, const int* __restrict__ edst,
                            int* __restrict__ cur, int* __restrict__ col) {
    int tot = NREL * NEDGES;
    for (int i = blockIdx.x * blockDim.x + threadIdx.x; i < tot; i += gridDim.x * blockDim.x) {
        int r = i / NEDGES;
        int d = edst[i];
        int pos = atomicAdd(&cur[r * NNODES + d], 1);
        col[r * NEDGES + pos] = esrc[i];
    }
}

// ---------------- aggregation: one wave per (node, rel) ----------------
// out[rel][node][f] = (sum_{e in CSR_rel[node]} src[col[e]][f]) / max(deg,1), bf16

__global__ __launch_bounds__(256) void aggregate_kernel(const u16* __restrict__ src,
                                                        const int* __restrict__ rp,
                                                        const int* __restrict__ col,
                                                        u16* __restrict__ out) {
    int node = blockIdx.x * 4 + (threadIdx.x >> 6);
    int rel = blockIdx.y;
    if (node >= NNODES) return;
    const int* r = rp + rel * (NNODES + 1);
    const int* cl = col + rel * NEDGES;
    int l = threadIdx.x & 63;
    int p0 = r[node], p1 = r[node + 1];
    float scale = (p1 > p0) ? 1.0f / (float)(p1 - p0) : 1.0f;
    float acc[8] = {0.f, 0.f, 0.f, 0.f, 0.f, 0.f, 0.f, 0.f};
    int e = p0;
    for (; e + 2 <= p1; e += 2) {   // 2-deep unroll: two independent row loads in flight
        int s0 = cl[e], s1 = cl[e + 1];
        u16x8 v0 = *(const u16x8*)(src + (size_t)s0 * 512 + l * 8);
        u16x8 v1 = *(const u16x8*)(src + (size_t)s1 * 512 + l * 8);
#pragma unroll
        for (int j = 0; j < 8; ++j) acc[j] += bf2f(v0[j]) + bf2f(v1[j]);
    }
    if (e < p1) {
        int s0 = cl[e];
        u16x8 v0 = *(const u16x8*)(src + (size_t)s0 * 512 + l * 8);
#pragma unroll
        for (int j = 0; j < 8; ++j) acc[j] += bf2f(v0[j]);
    }
    u16x8 o;
#pragma unroll
    for (int j = 0; j < 8; ++j) o[j] = f2bf(acc[j] * scale);
    *(u16x8*)(out + ((size_t)rel * NNODES + node) * 512 + l * 8) = o;
}

// ---------------- GEMM: C[M][N] = concat_K(A0..A4) @ WT^T + bias ----------------
// A_s: [M][512] bf16 row-major.  WT: [N][2560] bf16 row-major (pre-transposed weights).
// OUTMODE 0: out = bf16(relu(acc+bias));  OUTMODE 1: out = f32(acc+bias)
// Grid: dim3(N/128, nrowblk). Block id is remapped (bijective XCD chunking, m204) so the
// ncol column-blocks sharing one A row-panel dispatch adjacently AND on the same XCD ->
// A panel fetched from HBM once, reused via L2.

template <int N, int OUTMODE>
__global__ __launch_bounds__(256, 4) void gemm_kernel(
    const u16* __restrict__ A0, const u16* __restrict__ A1, const u16* __restrict__ A2,
    const u16* __restrict__ A3, const u16* __restrict__ A4, const u16* __restrict__ WT,
    const float* __restrict__ bias, void* __restrict__ outp, int M) {
    __shared__ u16 ldsA[128 * 64];
    __shared__ u16 ldsB[128 * 64];
    const int t = threadIdx.x;
    const int w = t >> 6, l = t & 63;
    const int wr = w >> 1, wc = w & 1;

    constexpr int ncol = N >> 7;
    const int nwg = gridDim.x * gridDim.y;
    const int orig = blockIdx.y * gridDim.x + blockIdx.x;  // hardware dispatch order
    const int q = nwg >> 3, rr = nwg & 7, xcd = orig & 7, loc = orig >> 3;
    const int v = (xcd < rr) ? xcd * (q + 1) + loc : rr * (q + 1) + (xcd - rr) * q + loc;
    const int rowBase = (v / ncol) * 128;
    const int colBase = (v % ncol) * 128;

    f32x4 acc[4][4] = {};

    const u16* const As[5] = {A0, A1, A2, A3, A4};
    const int sr = t >> 3;       // 0..31 staging row within a call
    const int gp = t & 7;        // physical granule (16B)
    const int lr = l & 15, lg = l >> 4;

#pragma unroll
    for (int s = 0; s < 5; ++s) {
        const u16* __restrict__ Asrc = As[s];
        for (int ts = 0; ts < 8; ++ts) {
            const int klocal = ts * 64;
            const int kglob = s * 512 + klocal;
            // stage A tile (128 x 64 bf16), pre-swizzled source, linear LDS dest
#pragma unroll
            for (int c = 0; c < 4; ++c) {
                int r = c * 32 + sr;
                int gl = gp ^ (r & 7);
                int grow = rowBase + r;
                if (grow > M - 1) grow = M - 1;
                const u16* gsrc = Asrc + (size_t)grow * 512 + klocal + gl * 8;
                GLOAD_LDS16(gsrc, ldsA + (c * 2048 + w * 512));
            }
            // stage B tile (128 output-cols x 64 k)
#pragma unroll
            for (int c = 0; c < 4; ++c) {
                int r = c * 32 + sr;
                int gl = gp ^ (r & 7);
                const u16* gsrc = WT + (size_t)(colBase + r) * KCAT + kglob + gl * 8;
                GLOAD_LDS16(gsrc, ldsB + (c * 2048 + w * 512));
            }
            __syncthreads();   // drains vmcnt before any wave reads LDS
#pragma unroll
            for (int kh = 0; kh < 2; ++kh) {
                bf16x8 av[4], bv[4];
#pragma unroll
                for (int m = 0; m < 4; ++m) {
                    int r = wr * 64 + m * 16 + lr;
                    int g = (kh * 4 + lg) ^ (r & 7);
                    av[m] = *(const bf16x8*)((const char*)ldsA + r * 128 + g * 16);
                }
#pragma unroll
                for (int n = 0; n < 4; ++n) {
                    int r = wc * 64 + n * 16 + lr;
                    int g = (kh * 4 + lg) ^ (r & 7);
                    bv[n] = *(const bf16x8*)((const char*)ldsB + r * 128 + g * 16);
                }
#pragma unroll
                for (int m = 0; m < 4; ++m)
#pragma unroll
                    for (int n = 0; n < 4; ++n)
                        acc[m][n] =
                            __builtin_amdgcn_mfma_f32_16x16x32_bf16(av[m], bv[n], acc[m][n], 0, 0, 0);
            }
            __syncthreads();   // compute done before next stage overwrites
        }
    }

    const int lq = l >> 4;
#pragma unroll
    for (int m = 0; m < 4; ++m) {
#pragma unroll
        for (int n = 0; n < 4; ++n) {
#pragma unroll
            for (int j = 0; j < 4; ++j) {
                int row = rowBase + wr * 64 + m * 16 + lq * 4 + j;
                int colc = colBase + wc * 64 + n * 16 + lr;
                if (row < M) {
                    float vv = acc[m][n][j] + bias[colc];
                    if (OUTMODE == 0) {
                        vv = vv > 0.f ? vv : 0.f;
                        ((u16*)outp)[(size_t)row * N + colc] = f2bf(vv);
                    } else {
                        ((float*)outp)[(size_t)row * N + colc] = vv;
                    }
                }
            }
        }
    }
}

// ---------------- host ----------------

extern "C" void kernel_launch(void* const* d_in, const int* in_sizes, int n_in,
                              void* d_out, int out_size, void* d_ws, size_t ws_size,
                              hipStream_t stream) {
    const float* x = (const float*)d_in[0];
    const float* Wself1 = (const float*)d_in[1];
    const float* Wneigh1 = (const float*)d_in[2];
    const float* b1 = (const float*)d_in[3];
    const float* Wself2 = (const float*)d_in[4];
    const float* Wneigh2 = (const float*)d_in[5];
    const float* b2 = (const float*)d_in[6];
    const int* esrc = (const int*)d_in[7];
    const int* edst = (const int*)d_in[8];

    char* ws = (char*)d_ws;
    size_t off = 0;
    auto alloc = [&](size_t bytes) {
        char* p = ws + off;
        off += (bytes + 255) & ~(size_t)255;
        return p;
    };
    const size_t plane = (size_t)NNODES * 512;
    u16* xB = (u16*)alloc(plane * 2);             // x in bf16
    u16* mB = (u16*)alloc(NREL * plane * 2);      // 4 aggregate buffers
    u16* h1B = (u16*)alloc(plane * 2);            // relu(h1) in bf16
    u16* WT1 = (u16*)alloc((size_t)HIDF * KCAT * 2);
    u16* WT2 = (u16*)alloc((size_t)OUTF * KCAT * 2);
    float* b1s = (float*)alloc(HIDF * 4);
    float* b2s = (float*)alloc(OUTF * 4);
    int* deg = (int*)alloc((size_t)NREL * NNODES * 4);
    int* rp = (int*)alloc((size_t)NREL * (NNODES + 1) * 4);
    int* cur = (int*)alloc((size_t)NREL * NNODES * 4);
    int* col = (int*)alloc((size_t)NREL * NEDGES * 4);
    int* bsum = (int*)alloc((size_t)NREL * SCANB * 4);
    int* bofs = (int*)alloc((size_t)NREL * SCANB * 4);

    hipMemsetAsync(deg, 0, (size_t)NREL * NNODES * 4, stream);
    cast_bf16_kernel<<<12500, 256, 0, stream>>>(x, xB, (long)NNODES * INF);
    prep_w_kernel<<<1280, 256, 0, stream>>>(Wself1, Wneigh1, WT1, HIDF);
    prep_w_kernel<<<640, 256, 0, stream>>>(Wself2, Wneigh2, WT2, OUTF);
    prep_bias_kernel<<<1, 512, 0, stream>>>(b1, b2, b1s, b2s);
    hist_kernel<<<1024, 256, 0, stream>>>(edst, deg);
    scan1_kernel<<<NREL * SCANB, 1024, 0, stream>>>(deg, rp, bsum);
    scan2_kernel<<<1, 256, 0, stream>>>(bsum, bofs);
    scan3_kernel<<<NREL * SCANB, 1024, 0, stream>>>(rp, cur, bofs);
    fill_kernel<<<1024, 256, 0, stream>>>(esrc, edst, cur, col);

    // layer 1
    aggregate_kernel<<<dim3(12500, 4), 256, 0, stream>>>(xB, rp, col, mB);
    gemm_kernel<HIDF, 0><<<dim3(4, 391), 256, 0, stream>>>(
        xB, mB, mB + plane, mB + 2 * plane, mB + 3 * plane, WT1, b1s, h1B, NNODES);

    // layer 2
    aggregate_kernel<<<dim3(12500, 4), 256, 0, stream>>>(h1B, rp, col, mB);
    gemm_kernel<OUTF, 1><<<dim3(2, 391), 256, 0, stream>>>(
        h1B, mB, mB + plane, mB + 2 * plane, mB + 3 * plane, WT2, b2s, d_out, NNODES);
}